// Round 13
// baseline (253.552 us; speedup 1.0000x reference)
//
#include <hip/hip_runtime.h>
#include <math.h>

#define NN 3000
#define DD 30
#define NDIM 256
#define PI_F 3.14159265358979323846f

// ---- output layout (float offsets) ----
#define OF_FE  0          // features_e: 9000 x 512
#define OF_ADJ 4608000    // adj_la: 9000 x 9000
#define OF_NB  85608000   // neighbor_emb: 3000 x 1536
#define OF_FT  90216000   // ft|fv|fp: 3 x (3000 x 512)

// ---- workspace layout (float offsets) ----
#define WS_BLOCKS 0       // 90 * 100 * 100
#define WS_C01 900000
#define WS_C02 903000
#define WS_C12 906000
#define WS_DEG 909000     // 9000

// scratch in output regions (all consumed before final writers):
// NB: h0b @ +0, h1b @ +1.2M  (KE overwrites NB at the end)
// FT: WT @ +3.6M             (KE overwrites FT at the end)

// ---- K1 block-role ranges ----
#define K1_SPAR0 0        // 90   spital+sparsify+deg
#define K1_FILL0 90       // 2048 adj zero-fill
#define K1_GEMM0 2138     // 282  gemm1 (2 units each)
#define K1_PREP0 2420     // 1500 prep (2 rems each)
#define K1_WT0   3920     // 96   wtrans (2 tiles each)
#define K1_NBLK  4016

typedef __attribute__((ext_vector_type(8))) short bf16x8;
typedef __attribute__((ext_vector_type(4))) float f32x4;

__device__ __forceinline__ unsigned short f2bf(float x) {
  unsigned int u = __float_as_uint(x);
  return (unsigned short)((u + 0x7FFFu + ((u >> 16) & 1u)) >> 16);
}
__device__ __forceinline__ float bf2f(unsigned short u) {
  return __uint_as_float((unsigned int)u << 16);
}
__device__ __forceinline__ const float* xrow(int r, const float* t, const float* v, const float* p) {
  if (r < NN) return t + (size_t)r * NDIM;
  if (r < 2*NN) return v + (size_t)(r - NN) * NDIM;
  return p + (size_t)(r - 2*NN) * NDIM;
}
__device__ __forceinline__ bf16x8 ld8_f32(const float* q) {
  float4 a = *(const float4*)q;
  float4 b = *(const float4*)(q + 4);
  bf16x8 r;
  r[0] = (short)f2bf(a.x); r[1] = (short)f2bf(a.y); r[2] = (short)f2bf(a.z); r[3] = (short)f2bf(a.w);
  r[4] = (short)f2bf(b.x); r[5] = (short)f2bf(b.y); r[6] = (short)f2bf(b.z); r[7] = (short)f2bf(b.w);
  return r;
}
// B fragment (col, k0..k0+7) straight from row-major fp32 W (values == WT path)
__device__ __forceinline__ bf16x8 ldWcol(const float* __restrict__ W, int k0, int col) {
  bf16x8 r;
  #pragma unroll
  for (int j = 0; j < 8; ++j) r[j] = (short)f2bf(W[(size_t)(k0 + j) * 256 + col]);
  return r;
}

// ================= gemm1 body: fp32 X (t/v/p) x fp32 W0 -> h0b bf16 =================
__device__ __forceinline__ void gemm1_body(int gb, const float* __restrict__ t, const float* __restrict__ v,
                                           const float* __restrict__ p,
                                           const float* __restrict__ W0,
                                           const float* __restrict__ b0,
                                           unsigned short* __restrict__ h0b, int tid) {
  int bx = gb & 3, by = gb >> 2;
  int row0 = by * 64, col0 = bx * 64;
  int wid = tid >> 6, lane = tid & 63;
  int wm = (wid >> 1) * 32, wn = (wid & 1) * 32;
  int fr = lane & 15, fk = (lane >> 4) * 8;
  int ra0 = row0 + wm + fr;       if (ra0 > 8999) ra0 = 8999;
  int ra1 = row0 + wm + 16 + fr;  if (ra1 > 8999) ra1 = 8999;
  const float* pa0 = xrow(ra0, t, v, p) + fk;
  const float* pa1 = xrow(ra1, t, v, p) + fk;
  int colB0 = col0 + wn + fr, colB1 = col0 + wn + 16 + fr;

  f32x4 a00 = {0.f,0.f,0.f,0.f}, a01 = a00, a10 = a00, a11 = a00;
  #pragma unroll
  for (int ks = 0; ks < 8; ++ks) {
    bf16x8 A0 = ld8_f32(pa0 + ks * 32);
    bf16x8 A1 = ld8_f32(pa1 + ks * 32);
    bf16x8 B0 = ldWcol(W0, ks * 32 + fk, colB0);
    bf16x8 B1 = ldWcol(W0, ks * 32 + fk, colB1);
    a00 = __builtin_amdgcn_mfma_f32_16x16x32_bf16(A0, B0, a00, 0, 0, 0);
    a01 = __builtin_amdgcn_mfma_f32_16x16x32_bf16(A0, B1, a01, 0, 0, 0);
    a10 = __builtin_amdgcn_mfma_f32_16x16x32_bf16(A1, B0, a10, 0, 0, 0);
    a11 = __builtin_amdgcn_mfma_f32_16x16x32_bf16(A1, B1, a11, 0, 0, 0);
  }
  #pragma unroll
  for (int mi = 0; mi < 2; ++mi) {
    #pragma unroll
    for (int ni = 0; ni < 2; ++ni) {
      f32x4 acc = (mi == 0) ? (ni == 0 ? a00 : a01) : (ni == 0 ? a10 : a11);
      #pragma unroll
      for (int rg = 0; rg < 4; ++rg) {
        int grow = row0 + wm + mi * 16 + (lane >> 4) * 4 + rg;
        int gcol = col0 + wn + ni * 16 + (lane & 15);
        if (grow < 9000) {
          float val = fmaxf(acc[rg] + b0[gcol], 0.0f);
          h0b[(size_t)grow * 256 + gcol] = f2bf(val);
        }
      }
    }
  }
}

// ================= K1: spital+sparsify+deg | fill | gemm1 | prep | wtrans =================
// All five roles are mutually independent (no cross-block deps within K1):
// spital+sparsify reads raw t/v/p and computes its own norms/cross-dots;
// gemm1 builds B-frags from raw fp32 W0; wtrans's WT is consumed in K2/K3 only.
#define LPAD 112
__global__ __launch_bounds__(512, 1) void k1_kernel(const float* __restrict__ t, const float* __restrict__ v,
                                                    const float* __restrict__ p, float* __restrict__ fe,
                                                    float* __restrict__ c01, float* __restrict__ c02,
                                                    float* __restrict__ c12,
                                                    const float* __restrict__ W0, const float* __restrict__ Ws,
                                                    unsigned short* __restrict__ WT,
                                                    float* __restrict__ blocks, float* __restrict__ deg,
                                                    float* __restrict__ adj,
                                                    const float* __restrict__ b0,
                                                    unsigned short* __restrict__ h0b) {
  __shared__ float smem[12360];   // 49.4 KB -> >=3 blocks/CU (LDS)
  int bid = blockIdx.x, tid = threadIdx.x;

  if (bid >= K1_WT0) {            // wtrans: 2 tiles per block
    int blk = (bid - K1_WT0) * 2 + (tid >> 8);
    int tid8 = tid & 255;
    float* T = smem + (tid >> 8) * 1056;
    int mm = blk >> 6, tt_ = blk & 63;
    int tr = (tt_ >> 3) * 32, tc = (tt_ & 7) * 32;
    const float* W = (mm == 0) ? W0 : Ws + (size_t)(mm - 1) * 65536;
    int r = tid8 >> 5, c = tid8 & 31;
    #pragma unroll
    for (int rr = 0; rr < 4; ++rr)
      T[(r + rr * 8) * 33 + c] = W[(size_t)(tr + r + rr * 8) * 256 + tc + c];
    __syncthreads();
    #pragma unroll
    for (int rr = 0; rr < 4; ++rr)
      WT[(size_t)mm * 65536 + (size_t)(tc + r + rr * 8) * 256 + tr + c] = f2bf(T[c * 33 + r + rr * 8]);
    return;
  }

  if (bid >= K1_PREP0) {          // prep: 2 rems per block
    int rem = (bid - K1_PREP0) * 2 + (tid >> 8);
    int tid8 = tid & 255;
    int w = tid8 >> 6, lane = tid8 & 63;
    float* NB = smem + (tid >> 8) * 768;
    if (w < 3) {
      const float* src = (w == 0 ? t : (w == 1 ? v : p)) + (size_t)rem * NDIM;
      float4 x = ((const float4*)src)[lane];
      int r = w * NN + rem;
      ((float4*)(fe + (size_t)r * 512))[lane] = x;
      float ss = x.x*x.x + x.y*x.y + x.z*x.z + x.w*x.w;
      #pragma unroll
      for (int off = 32; off > 0; off >>= 1) ss += __shfl_xor(ss, off);
      float inv = 1.0f / sqrtf(ss);
      float4 n = make_float4(x.x*inv, x.y*inv, x.z*inv, x.w*inv);
      ((float4*)&NB[w * 256])[lane] = n;
    }
    __syncthreads();
    if (w == 0) {
      float4 a = ((const float4*)&NB[0])[lane];
      float4 b = ((const float4*)&NB[256])[lane];
      float4 c = ((const float4*)&NB[512])[lane];
      float s01 = a.x*b.x + a.y*b.y + a.z*b.z + a.w*b.w;
      float s02 = a.x*c.x + a.y*c.y + a.z*c.z + a.w*c.w;
      float s12 = b.x*c.x + b.y*c.y + b.z*c.z + b.w*c.w;
      #pragma unroll
      for (int off = 32; off > 0; off >>= 1) {
        s01 += __shfl_xor(s01, off);
        s02 += __shfl_xor(s02, off);
        s12 += __shfl_xor(s12, off);
      }
      if (lane == 0) {
        c01[rem] = 1.0f - acosf(s01 * 0.99999f) / PI_F;
        c02[rem] = 1.0f - acosf(s02 * 0.99999f) / PI_F;
        c12[rem] = 1.0f - acosf(s12 * 0.99999f) / PI_F;
      }
    }
    return;
  }

  if (bid >= K1_GEMM0) {          // gemm1: 2 tile-units per block
    int gb = (bid - K1_GEMM0) * 2 + (tid >> 8);
    gemm1_body(gb, t, v, p, W0, b0, h0b, tid & 255);
    return;
  }

  if (bid >= K1_FILL0) {          // stream-zero adj (324 MB)
    float4 z = make_float4(0.f, 0.f, 0.f, 0.f);
    float4* adj4 = (float4*)adj;
    for (size_t u = (size_t)(bid - K1_FILL0) * 512 + tid; u < 20250000u; u += 2048u * 512u)
      adj4[u] = z;
    return;
  }

  // ---- role: spital + 4-deep sparsify + deg, bids [0,90) ----
  int b = bid, m = b / DD, d = b % DD;
  size_t off = (size_t)(d * 100) * NDIM;
  const float* tt = t + off; const float* vv = v + off; const float* pq = p + off;
  const float* xm = (m == 0) ? tt : (m == 1) ? vv : pq;
  int n1 = (m == 0) ? 1 : 0;
  int n2 = (m == 2) ? 1 : 2;
  const float* xn1 = (n1 == 0) ? tt : vv;
  const float* xn2 = (n2 == 1) ? vv : pq;
  float* ssl = smem;              // [5][112]: 0..2 sumsq(t,v,p); 3 dot(m,n1); 4 dot(m,n2)
  float* Ts  = smem + 560;        // [16][LPAD]
  float* A   = smem + 2352;       // [10000]

  if (tid < 500) {
    int task = tid / 100, i = tid % 100;
    const float* ra = (task == 0) ? tt : (task == 1) ? vv : (task == 2) ? pq : xm;
    const float* rb = (task == 3) ? xn1 : xn2;
    ra += (size_t)i * NDIM; rb += (size_t)i * NDIM;
    float s = 0.0f;
    if (task < 3) {
      for (int q = 0; q < 64; ++q) {
        float4 x = ((const float4*)ra)[q];
        s += x.x*x.x + x.y*x.y + x.z*x.z + x.w*x.w;
      }
    } else {
      for (int q = 0; q < 64; ++q) {
        float4 a4 = ((const float4*)ra)[q], b4 = ((const float4*)rb)[q];
        s += a4.x*b4.x + a4.y*b4.y + a4.z*b4.z + a4.w*b4.w;
      }
    }
    ssl[task * 112 + i] = s;
  }
  __syncthreads();

  // gram (16-k slabs), self-normalized; acc order == k ascending (bit-identical)
  int tn = tid & 15, tm = tid >> 4;
  float acc[7][7];
  #pragma unroll
  for (int q = 0; q < 7; ++q)
    #pragma unroll
    for (int s = 0; s < 7; ++s) acc[q][s] = 0.0f;
  for (int kk = 0; kk < 256; kk += 16) {
    for (int pp2 = tid; pp2 < 400; pp2 += 512) {
      int i = pp2 >> 2, q = pp2 & 3;
      float4 x = *(const float4*)&xm[(size_t)i * NDIM + kk + q * 4];
      float sc = 1.0f / sqrtf(ssl[m * 112 + i]);
      Ts[(q*4+0) * LPAD + i] = x.x * sc; Ts[(q*4+1) * LPAD + i] = x.y * sc;
      Ts[(q*4+2) * LPAD + i] = x.z * sc; Ts[(q*4+3) * LPAD + i] = x.w * sc;
    }
    __syncthreads();
    if (tid < 256) {
      #pragma unroll 4
      for (int k = 0; k < 16; ++k) {
        float a[7], bb[7];
        #pragma unroll
        for (int q = 0; q < 7; ++q) { int i = tm*7+q; if (i > 99) i = 99; a[q] = Ts[k * LPAD + i]; }
        #pragma unroll
        for (int s = 0; s < 7; ++s) { int j = tn*7+s; if (j > 99) j = 99; bb[s] = Ts[k * LPAD + j]; }
        #pragma unroll
        for (int q = 0; q < 7; ++q)
          #pragma unroll
          for (int s = 0; s < 7; ++s) acc[q][s] += a[q] * bb[s];
      }
    }
    __syncthreads();
  }
  if (tid < 256) {
    #pragma unroll
    for (int q = 0; q < 7; ++q) {
      int i = tm*7+q; if (i >= 100) continue;
      #pragma unroll
      for (int s = 0; s < 7; ++s) {
        int j = tn*7+s; if (j >= 100) continue;
        float S = acc[q][s] * 0.99999f;
        float sim = 1.0f - acosf(S) / PI_F;
        int dd = i - j; if (dd < 0) dd = -dd;
        float decay = logf((float)dd + 1.0f) + 1e-4f;
        A[i * 100 + j] = sim / decay;
      }
    }
  }
  __syncthreads();

  // 4-deep pipelined sequential scan (round-8 verbatim, A in LDS)
  int h = tid >> 7, i = tid & 127;
  for (int e = 0; e < 100; e += 4) {
    int er = e + h;
    float vi = 0.0f, w0 = 0.0f, w1 = 0.0f, w2 = 0.0f;
    int cnt = 0;
    if (i < 100) {
      vi = A[er * 100 + i];
      if (h > 0) w0 = A[er * 100 + e];
      if (h > 1) w1 = A[er * 100 + e + 1];
      if (h > 2) w2 = A[er * 100 + e + 2];
      int cA = 0, cB = 0, cC = 0, cD = 0;
      #pragma unroll
      for (int q = 0; q < 25; ++q) {
        float4 r4 = *(const float4*)&A[er * 100 + q * 4];
        cA += (int)(r4.x < vi); cB += (int)(r4.y < vi);
        cC += (int)(r4.z < vi); cD += (int)(r4.w < vi);
      }
      cnt = (cA + cB) + (cC + cD);
    }
    __syncthreads();
    if (h == 0 && i < 100 && cnt < 80 && vi != 0.0f) { A[e * 100 + i] = 0.0f; A[i * 100 + e] = 0.0f; }
    __syncthreads();
    if (h == 1 && i < 100) {
      float p0v = A[er * 100 + e];
      if (p0v == 0.0f && w0 != 0.0f) { if (i == e) vi = 0.0f; else cnt += 1 - (int)(w0 < vi); }
      if (cnt < 80 && vi != 0.0f) { A[er * 100 + i] = 0.0f; A[i * 100 + er] = 0.0f; }
    }
    __syncthreads();
    if (h == 2 && i < 100) {
      float p0v = A[er * 100 + e], p1v = A[er * 100 + e + 1];
      if (p0v == 0.0f && w0 != 0.0f) { if (i == e)     vi = 0.0f; else cnt += 1 - (int)(w0 < vi); }
      if (p1v == 0.0f && w1 != 0.0f) { if (i == e + 1) vi = 0.0f; else cnt += 1 - (int)(w1 < vi); }
      if (cnt < 80 && vi != 0.0f) { A[er * 100 + i] = 0.0f; A[i * 100 + er] = 0.0f; }
    }
    __syncthreads();
    if (h == 3 && i < 100) {
      float p0v = A[er * 100 + e], p1v = A[er * 100 + e + 1], p2v = A[er * 100 + e + 2];
      if (p0v == 0.0f && w0 != 0.0f) { if (i == e)     vi = 0.0f; else cnt += 1 - (int)(w0 < vi); }
      if (p1v == 0.0f && w1 != 0.0f) { if (i == e + 1) vi = 0.0f; else cnt += 1 - (int)(w1 < vi); }
      if (p2v == 0.0f && w2 != 0.0f) { if (i == e + 2) vi = 0.0f; else cnt += 1 - (int)(w2 < vi); }
      if (cnt < 80 && vi != 0.0f) { A[er * 100 + i] = 0.0f; A[i * 100 + er] = 0.0f; }
    }
    __syncthreads();
  }

  for (int p0 = tid; p0 < 10000; p0 += 512) blocks[(size_t)b * 10000 + p0] = A[p0];
  if (tid < 100) {
    float s = 0.0f;
    #pragma unroll
    for (int q = 0; q < 25; ++q) {
      float4 a4 = *(const float4*)&A[tid * 100 + q * 4];
      s += (a4.x + a4.y) + (a4.z + a4.w);
    }
    float invm = 1.0f / sqrtf(ssl[m * 112 + tid]);
    float inv1 = 1.0f / sqrtf(ssl[n1 * 112 + tid]);
    float inv2 = 1.0f / sqrtf(ssl[n2 * 112 + tid]);
    float ct1 = 1.0f - acosf(ssl[3 * 112 + tid] * invm * inv1 * 0.99999f) / PI_F;
    float ct2 = 1.0f - acosf(ssl[4 * 112 + tid] * invm * inv2 * 0.99999f) / PI_F;
    s += ct1 + ct2;
    if (s == 0.0f) s = 1e-12f;
    deg[m * NN + d * 100 + tid] = s;
  }
}

// ====== K2/K3: fused spmm (MFMA) + GCNII GEMM per (m,d), 90 blocks (round-8 form) ======
#define AVP 136
#define HTP 136
#define SUPP 264
__global__ __launch_bounds__(256, 1) void spmmgemm_kernel(const float* __restrict__ blocks,
                                                          const float* __restrict__ c01, const float* __restrict__ c02,
                                                          const float* __restrict__ c12, const float* __restrict__ deg,
                                                          const unsigned short* __restrict__ hin,
                                                          const unsigned short* __restrict__ hskip,
                                                          const unsigned short* __restrict__ WTl,
                                                          unsigned short* __restrict__ hout,
                                                          float* __restrict__ fe,
                                                          float* __restrict__ adj, int wadj,
                                                          float theta, float omtheta) {
  __shared__ unsigned short av[112 * AVP];
  __shared__ unsigned short hT[256 * HTP];
  __shared__ unsigned short sup[112 * SUPP];
  __shared__ float dcj[112], x1s[112], x2s[112];

  int b = blockIdx.x, m = b / DD, d = b % DD;
  int gbase = b * 100;
  int rem0 = d * 100;
  int tid = threadIdx.x;
  int n1, n2; const float *a1, *a2;
  if (m == 0)      { a1 = c01; a2 = c02; n1 = 1; n2 = 2; }
  else if (m == 1) { a1 = c01; a2 = c12; n1 = 0; n2 = 2; }
  else             { a1 = c02; a2 = c12; n1 = 0; n2 = 1; }

  if (tid < 100) {
    int rem = rem0 + tid;
    float dr_ = 1.0f / sqrtf(deg[gbase + tid]);
    dcj[tid] = dr_;
    x1s[tid] = a1[rem] * dr_ * (1.0f / sqrtf(deg[n1 * NN + rem]));
    x2s[tid] = a2[rem] * dr_ * (1.0f / sqrtf(deg[n2 * NN + rem]));
  }
  __syncthreads();

  for (int pp = tid; pp < 10000; pp += 256) {
    int i = pp / 100, j = pp % 100;
    av[i * AVP + j] = f2bf(blocks[(size_t)b * 10000 + pp] * dcj[j]);
  }
  for (int pp = tid; pp < 100 * 28; pp += 256) {
    int i = pp / 28, j = 100 + pp % 28;
    av[i * AVP + j] = 0;
  }
  {
    const unsigned short* hcol = hin + (size_t)gbase * 256 + tid;
    #pragma unroll 4
    for (int j = 0; j < 100; ++j) hT[tid * HTP + j] = hcol[(size_t)j * 256];
    #pragma unroll
    for (int j = 100; j < 128; ++j) hT[tid * HTP + j] = 0;
  }
  __syncthreads();

  int wid = tid >> 6, lane = tid & 63;
  int fr = lane & 15, fko = (lane >> 4) * 8;
  int wn = wid * 64;
  int rbase = (lane >> 4) * 4;

  f32x4 dacc[7][4];
  #pragma unroll
  for (int rt = 0; rt < 7; ++rt)
    #pragma unroll
    for (int ct = 0; ct < 4; ++ct) dacc[rt][ct] = (f32x4){0.f, 0.f, 0.f, 0.f};
  #pragma unroll
  for (int ks = 0; ks < 4; ++ks) {
    bf16x8 bfr[4];
    #pragma unroll
    for (int ct = 0; ct < 4; ++ct)
      bfr[ct] = *(const bf16x8*)&hT[(wn + ct * 16 + fr) * HTP + ks * 32 + fko];
    #pragma unroll
    for (int rt = 0; rt < 7; ++rt) {
      bf16x8 afr = *(const bf16x8*)&av[(rt * 16 + fr) * AVP + ks * 32 + fko];
      #pragma unroll
      for (int ct = 0; ct < 4; ++ct)
        dacc[rt][ct] = __builtin_amdgcn_mfma_f32_16x16x32_bf16(afr, bfr[ct], dacc[rt][ct], 0, 0, 0);
    }
  }
  size_t hb1 = ((size_t)n1 * NN + rem0) * 256;
  size_t hb2 = ((size_t)n2 * NN + rem0) * 256;
  size_t hbs = (size_t)gbase * 256;
  #pragma unroll
  for (int rt = 0; rt < 7; ++rt) {
    #pragma unroll
    for (int ct = 0; ct < 4; ++ct) {
      int col = wn + ct * 16 + fr;
      #pragma unroll
      for (int rg = 0; rg < 4; ++rg) {
        int rr = rt * 16 + rbase + rg;
        if (rr < 100) {
          float val = dacc[rt][ct][rg] * dcj[rr]
                    + x1s[rr] * bf2f(hin[hb1 + (size_t)rr * 256 + col])
                    + x2s[rr] * bf2f(hin[hb2 + (size_t)rr * 256 + col]);
          val = 0.9f * val + 0.1f * bf2f(hskip[hbs + (size_t)rr * 256 + col]);
          sup[rr * SUPP + col] = f2bf(val);
        }
      }
    }
  }
  if (wadj) {
    for (int pp = tid; pp < 10000; pp += 256) {
      int i = pp / 100, j = pp % 100;
      adj[(size_t)(gbase + i) * 9000 + gbase + j] = bf2f(av[i * AVP + j]) * dcj[i];
    }
    if (tid < 100) {
      float* rowp = adj + (size_t)(gbase + tid) * 9000;
      int rem = rem0 + tid;
      rowp[(size_t)n1 * NN + rem] = x1s[tid];
      rowp[(size_t)n2 * NN + rem] = x2s[tid];
    }
  }
  __syncthreads();

  f32x4 cacc[7][4];
  #pragma unroll
  for (int rt = 0; rt < 7; ++rt)
    #pragma unroll
    for (int ct = 0; ct < 4; ++ct) cacc[rt][ct] = (f32x4){0.f, 0.f, 0.f, 0.f};
  #pragma unroll
  for (int ks = 0; ks < 8; ++ks) {
    bf16x8 bfr[4];
    #pragma unroll
    for (int ct = 0; ct < 4; ++ct)
      bfr[ct] = *(const bf16x8*)&WTl[(size_t)(wn + ct * 16 + fr) * 256 + ks * 32 + fko];
    #pragma unroll
    for (int rt = 0; rt < 7; ++rt) {
      bf16x8 afr = *(const bf16x8*)&sup[(rt * 16 + fr) * SUPP + ks * 32 + fko];
      #pragma unroll
      for (int ct = 0; ct < 4; ++ct)
        cacc[rt][ct] = __builtin_amdgcn_mfma_f32_16x16x32_bf16(afr, bfr[ct], cacc[rt][ct], 0, 0, 0);
    }
  }
  #pragma unroll
  for (int rt = 0; rt < 7; ++rt) {
    #pragma unroll
    for (int ct = 0; ct < 4; ++ct) {
      int col = wn + ct * 16 + fr;
      #pragma unroll
      for (int rg = 0; rg < 4; ++rg) {
        int rr = rt * 16 + rbase + rg;
        if (rr < 100) {
          float sv = bf2f(sup[rr * SUPP + col]);
          float val = fmaxf(theta * cacc[rt][ct][rg] + omtheta * sv, 0.0f);
          if (hout) hout[(size_t)(gbase + rr) * 256 + col] = f2bf(val);
          else      fe[(size_t)(gbase + rr) * 512 + 256 + col] = val;
        }
      }
    }
  }
}

// ================= K4: neighbor_emb + ft/fv/fp fan-out =================
__global__ __launch_bounds__(256) void outfuse_kernel(const float* __restrict__ fe, float* __restrict__ out) {
  int rem = blockIdx.x, f = threadIdx.x;
  #pragma unroll
  for (int m = 0; m < 3; ++m) {
    size_t r = (size_t)(m * NN + rem);
    float xv = fe[r * 512 + f];
    float hv = fe[r * 512 + 256 + f];
    out[OF_NB + (size_t)rem * 1536 + m * 512 + f] = xv;
    out[OF_NB + (size_t)rem * 1536 + m * 512 + 256 + f] = hv;
    out[OF_FT + r * 512 + f] = xv;
    out[OF_FT + r * 512 + 256 + f] = hv;
  }
}

extern "C" void kernel_launch(void* const* d_in, const int* in_sizes, int n_in,
                              void* d_out, int out_size, void* d_ws, size_t ws_size,
                              hipStream_t stream) {
  const float* t  = (const float*)d_in[0];
  const float* v  = (const float*)d_in[1];
  const float* p  = (const float*)d_in[2];
  const float* W0 = (const float*)d_in[3];
  const float* b0 = (const float*)d_in[4];
  const float* Ws = (const float*)d_in[5];
  float* out = (float*)d_out;
  float* ws  = (float*)d_ws;

  float* blocks = ws + WS_BLOCKS;
  float* c01 = ws + WS_C01;
  float* c02 = ws + WS_C02;
  float* c12 = ws + WS_C12;
  float* deg = ws + WS_DEG;

  float* adj = out + OF_ADJ;
  float* fe  = out + OF_FE;

  unsigned short* h0b = (unsigned short*)(out + OF_NB);             // 9000x256 bf16
  unsigned short* h1b = (unsigned short*)(out + OF_NB + 1200000);
  unsigned short* WT  = (unsigned short*)(out + OF_FT + 3600000);   // 3 x 256x256 bf16

  // K1: spital+sparsify+deg | adj zero-fill | gemm1 | prep | wtrans
  k1_kernel<<<K1_NBLK, 512, 0, stream>>>(t, v, p, fe, c01, c02, c12, W0, Ws, WT,
                                         blocks, deg, adj, b0, h0b);
  // K2: layer 1 (spmm-MFMA + adj scatter + GEMM) -> h1
  spmmgemm_kernel<<<90, 256, 0, stream>>>(blocks, c01, c02, c12, deg, h0b, h0b, WT + 65536,
                                          h1b, nullptr, adj, 1,
                                          0.4054651081081644f, 0.5945348918918356f);
  // K3: layer 2 -> fe[:,256:]
  spmmgemm_kernel<<<90, 256, 0, stream>>>(blocks, c01, c02, c12, deg, h1b, h0b, WT + 131072,
                                          nullptr, fe, adj, 0,
                                          0.22314355131420976f, 0.7768564486857902f);
  // K4: fan out
  outfuse_kernel<<<3000, 256, 0, stream>>>(fe, out);
}

// Round 14
// 245.323 us; speedup vs baseline: 1.0335x; 1.0335x over previous
//
#include <hip/hip_runtime.h>
#include <math.h>

#define NN 3000
#define DD 30
#define NDIM 256
#define PI_F 3.14159265358979323846f

// ---- output layout (float offsets) ----
#define OF_FE  0          // features_e: 9000 x 512
#define OF_ADJ 4608000    // adj_la: 9000 x 9000
#define OF_NB  85608000   // neighbor_emb: 3000 x 1536
#define OF_FT  90216000   // ft|fv|fp: 3 x (3000 x 512)

// ---- workspace layout (float offsets) ----
#define WS_BLOCKS 0       // 90 * 100 * 100
#define WS_C01 900000
#define WS_C02 903000
#define WS_C12 906000
#define WS_DEG 909000     // 9000

// scratch in output regions (all consumed before final writers):
// NB: h0b @ +0, h1b @ +1.2M  (KE overwrites NB at the end)
// FT: WT @ +3.6M             (KE overwrites FT at the end)

typedef __attribute__((ext_vector_type(8))) short bf16x8;
typedef __attribute__((ext_vector_type(4))) float f32x4;

__device__ __forceinline__ unsigned short f2bf(float x) {
  unsigned int u = __float_as_uint(x);
  return (unsigned short)((u + 0x7FFFu + ((u >> 16) & 1u)) >> 16);
}
__device__ __forceinline__ float bf2f(unsigned short u) {
  return __uint_as_float((unsigned int)u << 16);
}
__device__ __forceinline__ const float* xrow(int r, const float* t, const float* v, const float* p) {
  if (r < NN) return t + (size_t)r * NDIM;
  if (r < 2*NN) return v + (size_t)(r - NN) * NDIM;
  return p + (size_t)(r - 2*NN) * NDIM;
}
__device__ __forceinline__ bf16x8 ld8_f32(const float* q) {
  float4 a = *(const float4*)q;
  float4 b = *(const float4*)(q + 4);
  bf16x8 r;
  r[0] = (short)f2bf(a.x); r[1] = (short)f2bf(a.y); r[2] = (short)f2bf(a.z); r[3] = (short)f2bf(a.w);
  r[4] = (short)f2bf(b.x); r[5] = (short)f2bf(b.y); r[6] = (short)f2bf(b.z); r[7] = (short)f2bf(b.w);
  return r;
}

// ================= KA: prep(3000) | wtrans(192) | spital-selfnorm(90) =================
#define LPAD 112
__global__ __launch_bounds__(256) void ka_kernel(const float* __restrict__ t, const float* __restrict__ v,
                                                 const float* __restrict__ p, float* __restrict__ fe,
                                                 float* __restrict__ c01, float* __restrict__ c02,
                                                 float* __restrict__ c12,
                                                 const float* __restrict__ W0, const float* __restrict__ Ws,
                                                 unsigned short* __restrict__ WT,
                                                 float* __restrict__ blocks) {
  __shared__ float smem[7280];
  int bid = blockIdx.x, tid = threadIdx.x;

  if (bid < 3000) {           // prep: fe x-half + cross sims
    int rem = bid;
    int w = tid >> 6, lane = tid & 63;
    if (w < 3) {
      const float* src = (w == 0 ? t : (w == 1 ? v : p)) + (size_t)rem * NDIM;
      float4 x = ((const float4*)src)[lane];
      int r = w * NN + rem;
      ((float4*)(fe + (size_t)r * 512))[lane] = x;
      float ss = x.x*x.x + x.y*x.y + x.z*x.z + x.w*x.w;
      #pragma unroll
      for (int off = 32; off > 0; off >>= 1) ss += __shfl_xor(ss, off);
      float inv = 1.0f / sqrtf(ss);
      float4 n = make_float4(x.x*inv, x.y*inv, x.z*inv, x.w*inv);
      ((float4*)&smem[w * 256])[lane] = n;
    }
    __syncthreads();
    if (w == 0) {
      float4 a = ((const float4*)&smem[0])[lane];
      float4 b = ((const float4*)&smem[256])[lane];
      float4 c = ((const float4*)&smem[512])[lane];
      float s01 = a.x*b.x + a.y*b.y + a.z*b.z + a.w*b.w;
      float s02 = a.x*c.x + a.y*c.y + a.z*c.z + a.w*c.w;
      float s12 = b.x*c.x + b.y*c.y + b.z*c.z + b.w*c.w;
      #pragma unroll
      for (int off = 32; off > 0; off >>= 1) {
        s01 += __shfl_xor(s01, off);
        s02 += __shfl_xor(s02, off);
        s12 += __shfl_xor(s12, off);
      }
      if (lane == 0) {
        c01[rem] = 1.0f - acosf(s01 * 0.99999f) / PI_F;
        c02[rem] = 1.0f - acosf(s02 * 0.99999f) / PI_F;
        c12[rem] = 1.0f - acosf(s12 * 0.99999f) / PI_F;
      }
    }
    return;
  }

  if (bid < 3192) {           // wtrans: 32x32 tile transpose fp32 -> bf16 WT[n][k]
    int blk = bid - 3000;
    int m = blk >> 6, tt = blk & 63;
    int tr = (tt >> 3) * 32, tc = (tt & 7) * 32;
    const float* W = (m == 0) ? W0 : Ws + (size_t)(m - 1) * 65536;
    int r = tid >> 5, c = tid & 31;
    #pragma unroll
    for (int rr = 0; rr < 4; ++rr)
      smem[(r + rr * 8) * 33 + c] = W[(size_t)(tr + r + rr * 8) * 256 + tc + c];
    __syncthreads();
    #pragma unroll
    for (int rr = 0; rr < 4; ++rr)
      WT[(size_t)m * 65536 + (size_t)(tc + r + rr * 8) * 256 + tr + c] = f2bf(smem[c * 33 + r + rr * 8]);
    return;
  }

  // spital with self-normalization
  int b = bid - 3192;
  int m = b / DD, d = b % DD;
  const float* src = (m == 0 ? t : (m == 1 ? v : p)) + (size_t)(d * 100) * NDIM;
  float* Ts = smem;
  float* nrm = &smem[7168];
  if (tid < 200) {
    int i = tid >> 1, hf = tid & 1;
    const float* rp = src + (size_t)i * 256 + hf * 128;
    float ss = 0.0f;
    #pragma unroll
    for (int q = 0; q < 32; ++q) {
      float4 x = ((const float4*)rp)[q];
      ss += x.x*x.x + x.y*x.y + x.z*x.z + x.w*x.w;
    }
    ss += __shfl_xor(ss, 1);
    if (hf == 0) nrm[i] = 1.0f / sqrtf(ss);
  }
  __syncthreads();

  int tn = tid & 15, tm = tid >> 4;
  float acc[7][7];
  #pragma unroll
  for (int q = 0; q < 7; ++q)
    #pragma unroll
    for (int s = 0; s < 7; ++s) acc[q][s] = 0.0f;

  for (int kk = 0; kk < 256; kk += 64) {
    for (int pp = tid; pp < 1600; pp += 256) {
      int kq = pp & 15, i = pp >> 4;
      float4 vv = *(const float4*)&src[(size_t)i * 256 + kk + kq * 4];
      float sc = nrm[i];
      Ts[(kq*4+0) * LPAD + i] = vv.x * sc; Ts[(kq*4+1) * LPAD + i] = vv.y * sc;
      Ts[(kq*4+2) * LPAD + i] = vv.z * sc; Ts[(kq*4+3) * LPAD + i] = vv.w * sc;
    }
    __syncthreads();
    #pragma unroll 4
    for (int k = 0; k < 64; ++k) {
      float a[7], bb[7];
      #pragma unroll
      for (int q = 0; q < 7; ++q) { int i = tm*7+q; if (i > 99) i = 99; a[q] = Ts[k * LPAD + i]; }
      #pragma unroll
      for (int s = 0; s < 7; ++s) { int j = tn*7+s; if (j > 99) j = 99; bb[s] = Ts[k * LPAD + j]; }
      #pragma unroll
      for (int q = 0; q < 7; ++q)
        #pragma unroll
        for (int s = 0; s < 7; ++s) acc[q][s] += a[q] * bb[s];
    }
    __syncthreads();
  }
  #pragma unroll
  for (int q = 0; q < 7; ++q) {
    int i = tm*7+q; if (i >= 100) continue;
    #pragma unroll
    for (int s = 0; s < 7; ++s) {
      int j = tn*7+s; if (j >= 100) continue;
      float S = acc[q][s] * 0.99999f;
      float sim = 1.0f - acosf(S) / PI_F;
      int dd = i - j; if (dd < 0) dd = -dd;
      float decay = logf((float)dd + 1.0f) + 1e-4f;
      blocks[(size_t)b * 10000 + i * 100 + j] = sim / decay;
    }
  }
}

// ================= gemm1 body: fp32 A (t/v/p) x bf16 WT -> h0b bf16 =================
__device__ __forceinline__ void gemm1_body(int gb, const float* __restrict__ t, const float* __restrict__ v,
                                           const float* __restrict__ p,
                                           const unsigned short* __restrict__ WT,
                                           const float* __restrict__ b0,
                                           unsigned short* __restrict__ h0b, int tid) {
  int bx = gb & 3, by = gb >> 2;
  int row0 = by * 64, col0 = bx * 64;
  int wid = tid >> 6, lane = tid & 63;
  int wm = (wid >> 1) * 32, wn = (wid & 1) * 32;
  int fr = lane & 15, fk = (lane >> 4) * 8;
  int ra0 = row0 + wm + fr;       if (ra0 > 8999) ra0 = 8999;
  int ra1 = row0 + wm + 16 + fr;  if (ra1 > 8999) ra1 = 8999;
  const float* pa0 = xrow(ra0, t, v, p) + fk;
  const float* pa1 = xrow(ra1, t, v, p) + fk;
  const unsigned short* pb0 = WT + (size_t)(col0 + wn + fr) * 256 + fk;
  const unsigned short* pb1 = WT + (size_t)(col0 + wn + 16 + fr) * 256 + fk;

  f32x4 a00 = {0.f,0.f,0.f,0.f}, a01 = a00, a10 = a00, a11 = a00;
  #pragma unroll
  for (int ks = 0; ks < 8; ++ks) {
    bf16x8 A0 = ld8_f32(pa0 + ks * 32);
    bf16x8 A1 = ld8_f32(pa1 + ks * 32);
    bf16x8 B0 = *(const bf16x8*)(pb0 + ks * 32);
    bf16x8 B1 = *(const bf16x8*)(pb1 + ks * 32);
    a00 = __builtin_amdgcn_mfma_f32_16x16x32_bf16(A0, B0, a00, 0, 0, 0);
    a01 = __builtin_amdgcn_mfma_f32_16x16x32_bf16(A0, B1, a01, 0, 0, 0);
    a10 = __builtin_amdgcn_mfma_f32_16x16x32_bf16(A1, B0, a10, 0, 0, 0);
    a11 = __builtin_amdgcn_mfma_f32_16x16x32_bf16(A1, B1, a11, 0, 0, 0);
  }
  #pragma unroll
  for (int mi = 0; mi < 2; ++mi) {
    #pragma unroll
    for (int ni = 0; ni < 2; ++ni) {
      f32x4 acc = (mi == 0) ? (ni == 0 ? a00 : a01) : (ni == 0 ? a10 : a11);
      #pragma unroll
      for (int rg = 0; rg < 4; ++rg) {
        int grow = row0 + wm + mi * 16 + (lane >> 4) * 4 + rg;
        int gcol = col0 + wn + ni * 16 + (lane & 15);
        if (grow < 9000) {
          float val = fmaxf(acc[rg] + b0[gcol], 0.0f);
          h0b[(size_t)grow * 256 + gcol] = f2bf(val);
        }
      }
    }
  }
}

// ====== KB: sparsify(90, 4-deep) | adj zero-fill(2048) | gemm1(282 blocks x 2 units) ======
__global__ __launch_bounds__(512, 1) void kb_kernel(float* __restrict__ blocks,
                                                    const float* __restrict__ c01, const float* __restrict__ c02,
                                                    const float* __restrict__ c12, float* __restrict__ deg,
                                                    float* __restrict__ adj,
                                                    const float* __restrict__ t, const float* __restrict__ v,
                                                    const float* __restrict__ p,
                                                    const unsigned short* __restrict__ WT,
                                                    const float* __restrict__ b0,
                                                    unsigned short* __restrict__ h0b) {
  __shared__ float A[10000];
  int bid = blockIdx.x, tid = threadIdx.x;

  if (bid >= 2138) {                         // gemm1, two 64x64 tiles per block
    int gb = (bid - 2138) * 2 + (tid >> 8);
    gemm1_body(gb, t, v, p, WT, b0, h0b, tid & 255);
    return;
  }
  if (bid >= 90) {                           // stream-zero adj (324 MB)
    float4 z = make_float4(0.f, 0.f, 0.f, 0.f);
    float4* adj4 = (float4*)adj;
    for (size_t u = (size_t)(bid - 90) * 512 + tid; u < 20250000u; u += 2048u * 512u)
      adj4[u] = z;
    return;
  }

  // sparsify: 4-deep pipelined sequential scan (bit-identical decisions)
  int b = bid, m = b / DD, d = b % DD;
  for (int p0 = tid; p0 < 10000; p0 += 512) A[p0] = blocks[(size_t)b * 10000 + p0];
  __syncthreads();
  int h = tid >> 7, i = tid & 127;
  for (int e = 0; e < 100; e += 4) {
    int er = e + h;
    float vi = 0.0f, w0 = 0.0f, w1 = 0.0f, w2 = 0.0f;
    int cnt = 0;
    if (i < 100) {
      vi = A[er * 100 + i];
      if (h > 0) w0 = A[er * 100 + e];
      if (h > 1) w1 = A[er * 100 + e + 1];
      if (h > 2) w2 = A[er * 100 + e + 2];
      int cA = 0, cB = 0, cC = 0, cD = 0;
      #pragma unroll
      for (int q = 0; q < 25; ++q) {
        float4 r4 = *(const float4*)&A[er * 100 + q * 4];
        cA += (int)(r4.x < vi); cB += (int)(r4.y < vi);
        cC += (int)(r4.z < vi); cD += (int)(r4.w < vi);
      }
      cnt = (cA + cB) + (cC + cD);
    }
    __syncthreads();
    if (h == 0 && i < 100 && cnt < 80 && vi != 0.0f) { A[e * 100 + i] = 0.0f; A[i * 100 + e] = 0.0f; }
    __syncthreads();
    if (h == 1 && i < 100) {
      float p0v = A[er * 100 + e];
      if (p0v == 0.0f && w0 != 0.0f) { if (i == e) vi = 0.0f; else cnt += 1 - (int)(w0 < vi); }
      if (cnt < 80 && vi != 0.0f) { A[er * 100 + i] = 0.0f; A[i * 100 + er] = 0.0f; }
    }
    __syncthreads();
    if (h == 2 && i < 100) {
      float p0v = A[er * 100 + e], p1v = A[er * 100 + e + 1];
      if (p0v == 0.0f && w0 != 0.0f) { if (i == e)     vi = 0.0f; else cnt += 1 - (int)(w0 < vi); }
      if (p1v == 0.0f && w1 != 0.0f) { if (i == e + 1) vi = 0.0f; else cnt += 1 - (int)(w1 < vi); }
      if (cnt < 80 && vi != 0.0f) { A[er * 100 + i] = 0.0f; A[i * 100 + er] = 0.0f; }
    }
    __syncthreads();
    if (h == 3 && i < 100) {
      float p0v = A[er * 100 + e], p1v = A[er * 100 + e + 1], p2v = A[er * 100 + e + 2];
      if (p0v == 0.0f && w0 != 0.0f) { if (i == e)     vi = 0.0f; else cnt += 1 - (int)(w0 < vi); }
      if (p1v == 0.0f && w1 != 0.0f) { if (i == e + 1) vi = 0.0f; else cnt += 1 - (int)(w1 < vi); }
      if (p2v == 0.0f && w2 != 0.0f) { if (i == e + 2) vi = 0.0f; else cnt += 1 - (int)(w2 < vi); }
      if (cnt < 80 && vi != 0.0f) { A[er * 100 + i] = 0.0f; A[i * 100 + er] = 0.0f; }
    }
    __syncthreads();
  }
  for (int p0 = tid; p0 < 10000; p0 += 512) blocks[(size_t)b * 10000 + p0] = A[p0];
  if (tid < 100) {
    float s = 0.0f;
    #pragma unroll
    for (int q = 0; q < 25; ++q) {
      float4 a4 = *(const float4*)&A[tid * 100 + q * 4];
      s += (a4.x + a4.y) + (a4.z + a4.w);
    }
    int rem = d * 100 + tid;
    float ct = (m == 0) ? c01[rem] + c02[rem] : (m == 1) ? c01[rem] + c12[rem] : c02[rem] + c12[rem];
    s += ct;
    if (s == 0.0f) s = 1e-12f;
    deg[m * NN + rem] = s;
  }
}

// ====== K2/K3: row-split fused spmm (MFMA) + GCNII GEMM, 180 blocks ======
// Block (b, bh) owns local rows [bh*64, bh*64+64) of the 112-row tile
// (global rows r0..r0+63, guarded <100). Values bit-identical to the
// 90-block version: same fragments, same accumulation order.
#define AVP 136
#define HTP 136
#define SUPP 264
__global__ __launch_bounds__(256, 1) void spmmgemm_kernel(const float* __restrict__ blocks,
                                                          const float* __restrict__ c01, const float* __restrict__ c02,
                                                          const float* __restrict__ c12, const float* __restrict__ deg,
                                                          const unsigned short* __restrict__ hin,
                                                          const unsigned short* __restrict__ hskip,
                                                          const unsigned short* __restrict__ WTl,
                                                          unsigned short* __restrict__ hout,
                                                          float* __restrict__ fe,
                                                          float* __restrict__ adj, int wadj,
                                                          float theta, float omtheta) {
  __shared__ unsigned short av[64 * AVP];
  __shared__ unsigned short hT[256 * HTP];
  __shared__ unsigned short sup[64 * SUPP];
  __shared__ float dcj[112], x1s[112], x2s[112];

  int b = blockIdx.x >> 1, bh = blockIdx.x & 1;
  int r0 = bh << 6;                 // 0 or 64
  int m = b / DD, d = b % DD;
  int gbase = b * 100;              // == m*NN + d*100 (global node base)
  int rem0 = d * 100;
  int tid = threadIdx.x;
  int n1, n2; const float *a1, *a2;
  if (m == 0)      { a1 = c01; a2 = c02; n1 = 1; n2 = 2; }
  else if (m == 1) { a1 = c01; a2 = c12; n1 = 0; n2 = 2; }
  else             { a1 = c02; a2 = c12; n1 = 0; n2 = 1; }

  if (tid < 100) {
    int rem = rem0 + tid;
    float dr_ = 1.0f / sqrtf(deg[gbase + tid]);
    dcj[tid] = dr_;
    x1s[tid] = a1[rem] * dr_ * (1.0f / sqrtf(deg[n1 * NN + rem]));
    x2s[tid] = a2[rem] * dr_ * (1.0f / sqrtf(deg[n2 * NN + rem]));
  }
  __syncthreads();

  // stage AV rows [r0, r0+64) (col-scaled, bf16); zero rows >=100 and K-pad
  for (int pp = tid; pp < 6400; pp += 256) {
    int lr = pp / 100, j = pp % 100;
    int gi = r0 + lr;
    av[lr * AVP + j] = (gi < 100) ? f2bf(blocks[(size_t)b * 10000 + gi * 100 + j] * dcj[j])
                                  : (unsigned short)0;
  }
  for (int pp = tid; pp < 64 * 28; pp += 256) {
    int lr = pp / 28, j = 100 + pp % 28;
    av[lr * AVP + j] = 0;
  }
  // pre-zero sup pad rows (global >=100) so phase-2 reads defined data
  if (r0 + 63 >= 100) {
    int pad0 = 100 - r0;                     // first pad local row (36 for bh=1)
    for (int pp = tid; pp < (64 - pad0) * SUPP; pp += 256)
      sup[pad0 * SUPP + pp] = 0;
  }
  // stage hT[f][j] (full, duplicated across halves) + zero K-pad
  {
    const unsigned short* hcol = hin + (size_t)gbase * 256 + tid;
    #pragma unroll 4
    for (int j = 0; j < 100; ++j) hT[tid * HTP + j] = hcol[(size_t)j * 256];
    #pragma unroll
    for (int j = 100; j < 128; ++j) hT[tid * HTP + j] = 0;
  }
  __syncthreads();

  int wid = tid >> 6, lane = tid & 63;
  int fr = lane & 15, fko = (lane >> 4) * 8;
  int wn = wid * 64;
  int rbase = (lane >> 4) * 4;

  // MFMA phase 1: D(64x256) = AV(64x128) @ H ; this wave: cols [wn, wn+64)
  f32x4 dacc[4][4];
  #pragma unroll
  for (int rt = 0; rt < 4; ++rt)
    #pragma unroll
    for (int ct = 0; ct < 4; ++ct) dacc[rt][ct] = (f32x4){0.f, 0.f, 0.f, 0.f};
  #pragma unroll
  for (int ks = 0; ks < 4; ++ks) {
    bf16x8 bfr[4];
    #pragma unroll
    for (int ct = 0; ct < 4; ++ct)
      bfr[ct] = *(const bf16x8*)&hT[(wn + ct * 16 + fr) * HTP + ks * 32 + fko];
    #pragma unroll
    for (int rt = 0; rt < 4; ++rt) {
      bf16x8 afr = *(const bf16x8*)&av[(rt * 16 + fr) * AVP + ks * 32 + fko];
      #pragma unroll
      for (int ct = 0; ct < 4; ++ct)
        dacc[rt][ct] = __builtin_amdgcn_mfma_f32_16x16x32_bf16(afr, bfr[ct], dacc[rt][ct], 0, 0, 0);
    }
  }
  // epilogue 1: support with row scale + cross-modality + skip -> sup (bf16)
  size_t hb1 = ((size_t)n1 * NN + rem0) * 256;
  size_t hb2 = ((size_t)n2 * NN + rem0) * 256;
  size_t hbs = (size_t)gbase * 256;
  #pragma unroll
  for (int rt = 0; rt < 4; ++rt) {
    #pragma unroll
    for (int ct = 0; ct < 4; ++ct) {
      int col = wn + ct * 16 + fr;
      #pragma unroll
      for (int rg = 0; rg < 4; ++rg) {
        int lr = rt * 16 + rbase + rg;
        int rr = r0 + lr;
        if (rr < 100) {
          float val = dacc[rt][ct][rg] * dcj[rr]
                    + x1s[rr] * bf2f(hin[hb1 + (size_t)rr * 256 + col])
                    + x2s[rr] * bf2f(hin[hb2 + (size_t)rr * 256 + col]);
          val = 0.9f * val + 0.1f * bf2f(hskip[hbs + (size_t)rr * 256 + col]);
          sup[lr * SUPP + col] = f2bf(val);
        }
      }
    }
  }
  // adj nonzero scatter (layer 1 only), rows of this half
  if (wadj) {
    int nrow = 100 - r0; if (nrow > 64) nrow = 64;
    for (int pp = tid; pp < nrow * 100; pp += 256) {
      int lr = pp / 100, j = pp % 100;
      int gi = r0 + lr;
      adj[(size_t)(gbase + gi) * 9000 + gbase + j] = bf2f(av[lr * AVP + j]) * dcj[gi];
    }
    if (tid < 64 && r0 + tid < 100) {
      int rr = r0 + tid;
      float* rowp = adj + (size_t)(gbase + rr) * 9000;
      int rem = rem0 + rr;
      rowp[(size_t)n1 * NN + rem] = x1s[rr];
      rowp[(size_t)n2 * NN + rem] = x2s[rr];
    }
  }
  __syncthreads();

  // MFMA phase 2: C(64x256) = sup(64x256) @ W
  f32x4 cacc[4][4];
  #pragma unroll
  for (int rt = 0; rt < 4; ++rt)
    #pragma unroll
    for (int ct = 0; ct < 4; ++ct) cacc[rt][ct] = (f32x4){0.f, 0.f, 0.f, 0.f};
  #pragma unroll
  for (int ks = 0; ks < 8; ++ks) {
    bf16x8 bfr[4];
    #pragma unroll
    for (int ct = 0; ct < 4; ++ct)
      bfr[ct] = *(const bf16x8*)&WTl[(size_t)(wn + ct * 16 + fr) * 256 + ks * 32 + fko];
    #pragma unroll
    for (int rt = 0; rt < 4; ++rt) {
      bf16x8 afr = *(const bf16x8*)&sup[(rt * 16 + fr) * SUPP + ks * 32 + fko];
      #pragma unroll
      for (int ct = 0; ct < 4; ++ct)
        cacc[rt][ct] = __builtin_amdgcn_mfma_f32_16x16x32_bf16(afr, bfr[ct], cacc[rt][ct], 0, 0, 0);
    }
  }
  // epilogue 2: h_next = relu(theta*C + omtheta*sup)
  #pragma unroll
  for (int rt = 0; rt < 4; ++rt) {
    #pragma unroll
    for (int ct = 0; ct < 4; ++ct) {
      int col = wn + ct * 16 + fr;
      #pragma unroll
      for (int rg = 0; rg < 4; ++rg) {
        int lr = rt * 16 + rbase + rg;
        int rr = r0 + lr;
        if (rr < 100) {
          float sv = bf2f(sup[lr * SUPP + col]);
          float val = fmaxf(theta * cacc[rt][ct][rg] + omtheta * sv, 0.0f);
          if (hout) hout[(size_t)(gbase + rr) * 256 + col] = f2bf(val);
          else      fe[(size_t)(gbase + rr) * 512 + 256 + col] = val;
        }
      }
    }
  }
}

// ================= KE: neighbor_emb + ft/fv/fp fan-out =================
__global__ __launch_bounds__(256) void outfuse_kernel(const float* __restrict__ fe, float* __restrict__ out) {
  int rem = blockIdx.x, f = threadIdx.x;
  #pragma unroll
  for (int m = 0; m < 3; ++m) {
    size_t r = (size_t)(m * NN + rem);
    float xv = fe[r * 512 + f];
    float hv = fe[r * 512 + 256 + f];
    out[OF_NB + (size_t)rem * 1536 + m * 512 + f] = xv;
    out[OF_NB + (size_t)rem * 1536 + m * 512 + 256 + f] = hv;
    out[OF_FT + r * 512 + f] = xv;
    out[OF_FT + r * 512 + 256 + f] = hv;
  }
}

extern "C" void kernel_launch(void* const* d_in, const int* in_sizes, int n_in,
                              void* d_out, int out_size, void* d_ws, size_t ws_size,
                              hipStream_t stream) {
  const float* t  = (const float*)d_in[0];
  const float* v  = (const float*)d_in[1];
  const float* p  = (const float*)d_in[2];
  const float* W0 = (const float*)d_in[3];
  const float* b0 = (const float*)d_in[4];
  const float* Ws = (const float*)d_in[5];
  float* out = (float*)d_out;
  float* ws  = (float*)d_ws;

  float* blocks = ws + WS_BLOCKS;
  float* c01 = ws + WS_C01;
  float* c02 = ws + WS_C02;
  float* c12 = ws + WS_C12;
  float* deg = ws + WS_DEG;

  float* adj = out + OF_ADJ;
  float* fe  = out + OF_FE;

  unsigned short* h0b = (unsigned short*)(out + OF_NB);             // 9000x256 bf16
  unsigned short* h1b = (unsigned short*)(out + OF_NB + 1200000);
  unsigned short* WT  = (unsigned short*)(out + OF_FT + 3600000);   // 3 x 256x256 bf16

  // KA: prep | wtrans | spital(self-norm)
  ka_kernel<<<3282, 256, 0, stream>>>(t, v, p, fe, c01, c02, c12, W0, Ws, WT, blocks);
  // KB: 4-deep sparsify | 324MB adj zero-fill | gemm1 (x @ W0 + b0 -> h0)
  kb_kernel<<<2420, 512, 0, stream>>>(blocks, c01, c02, c12, deg, adj, t, v, p, WT, b0, h0b);
  // K2: layer 1 (row-split spmm-MFMA + adj scatter + GEMM) -> h1
  spmmgemm_kernel<<<180, 256, 0, stream>>>(blocks, c01, c02, c12, deg, h0b, h0b, WT + 65536,
                                           h1b, nullptr, adj, 1,
                                           0.4054651081081644f, 0.5945348918918356f);
  // K3: layer 2 -> fe[:,256:]
  spmmgemm_kernel<<<180, 256, 0, stream>>>(blocks, c01, c02, c12, deg, h1b, h0b, WT + 131072,
                                           nullptr, fe, adj, 0,
                                           0.22314355131420976f, 0.7768564486857902f);
  // KE: fan out
  outfuse_kernel<<<3000, 256, 0, stream>>>(fe, out);
}